// Round 4
// baseline (391.597 us; speedup 1.0000x reference)
//
#include <hip/hip_runtime.h>
#include <stdint.h>

typedef int v4i __attribute__((ext_vector_type(4)));

static constexpr int MDIM = 8192;   // B * S
static constexpr int NDIM = 4096;   // D_OUT
static constexpr int KDIM = 4096;   // D_IN

static constexpr int QBLOCKS = (MDIM * KDIM / 16) / 256;  // 8192
static constexpr int WBLOCKS = (NDIM * KDIM / 16) / 256;  // 4096

// Async global->LDS, 16B per lane: HW writes lane i at (wave-uniform base) + i*16.
__device__ __forceinline__ void lds_load16(const void* gptr, void* lptr) {
    __builtin_amdgcn_global_load_lds(
        (const __attribute__((address_space(1))) void*)(uintptr_t)gptr,
        (__attribute__((address_space(3))) void*)(uint32_t)(uintptr_t)lptr,
        16, 0, 0);
}

__device__ __forceinline__ int q1(float f, float s) {
    return (int)fminf(fmaxf(__builtin_rintf(f / s), -128.0f), 127.0f);
}
__device__ __forceinline__ int pack4(int a, int b, int c, int d) {
    return (a & 0xff) | ((b & 0xff) << 8) | ((c & 0xff) << 16) | ((d & 0xff) << 24);
}

__global__ __launch_bounds__(256) void prep_k(const float4* __restrict__ x,
                                              int4* __restrict__ xq,
                                              const int4* __restrict__ w,
                                              int4* __restrict__ wq,
                                              const float* __restrict__ s_in) {
    const int b = blockIdx.x;
    if (b < QBLOCKS) {
        const int i = b * 256 + threadIdx.x;
        const float s = s_in[0];
        const float4 v0 = x[4 * i + 0];
        const float4 v1 = x[4 * i + 1];
        const float4 v2 = x[4 * i + 2];
        const float4 v3 = x[4 * i + 3];
        int4 o;
        o.x = pack4(q1(v0.x, s), q1(v0.y, s), q1(v0.z, s), q1(v0.w, s));
        o.y = pack4(q1(v1.x, s), q1(v1.y, s), q1(v1.z, s), q1(v1.w, s));
        o.z = pack4(q1(v2.x, s), q1(v2.y, s), q1(v2.z, s), q1(v2.w, s));
        o.w = pack4(q1(v3.x, s), q1(v3.y, s), q1(v3.z, s), q1(v3.w, s));
        xq[i] = o;
    } else {
        const int i = (b - QBLOCKS) * 256 + threadIdx.x;
        const int4 a = w[4 * i + 0];
        const int4 c = w[4 * i + 1];
        const int4 d = w[4 * i + 2];
        const int4 e = w[4 * i + 3];
        int4 o;
        o.x = pack4(a.x, a.y, a.z, a.w);
        o.y = pack4(c.x, c.y, c.z, c.w);
        o.z = pack4(d.x, d.y, d.z, d.w);
        o.w = pack4(e.x, e.y, e.z, e.w);
        wq[i] = o;
    }
}

// ============================================================================
// 256x256 tile, 8-phase, one barrier/phase, FULL one-phase-ahead fragment
// pipeline. LDS layout / swizzle / staging / epilogue identical to the
// verified 0-conflict kernel; only read-issue timing changes:
//
//  * Phase p issues ALL of phase p+1's fragment reads (av and bv both
//    double-buffered) BEFORE its own gate, so they drain under p's MFMA
//    burst. Gate at p = lgkmcnt(#reads just issued): waits only for reads
//    that already had a full MFMA window -> ~free. Even phases issue 4
//    (av only), odd phases issue 8 (bv group + av).
//  * Phases P0..P7 = (slot,ks,mh): (0,0,0)(0,0,1)(0,1,0)(0,1,1)
//    (1,0,0)(1,0,1)(1,1,0)(1,1,1). bv groups per (slot,ks) pair alternate
//    buffers 0,1,0,1; av alternates per phase (p consumes av[p&1]).
//  * WAR: each stage targets a region whose old reads drained >=1 barrier
//    earlier (all 4 regions verified; gates precede barrier arrival, stage
//    issues after the barrier). RAW: uniform VM6 (2 loads/phase) retires
//    each stage 3 phases after issue; first re-read of every region is >=4
//    phases after its stage (tightest: B-half retired at p, read at p+1 --
//    hence sched_barrier(0) after every s_barrier to forbid compile-time
//    hoisting of reads across the barrier). Peel: VM6,VM6,VM4,VM2,VM0.
// Stage schedule per iter i (tiles 2i=slot0, 2i+1=slot1):
//   P0/P1: s1.k1 (A,B) of tile 2i+1    P4/P5: s0.k1 (A,B) of tile 2i+2
//   P2/P3: s0.k0 (A,B) of tile 2i+2    P6/P7: s1.k0 (A,B) of tile 2i+3
// ============================================================================
__global__ __launch_bounds__(512, 2) void gemm_i8_k(const int8_t* __restrict__ A,
                                                    const int8_t* __restrict__ Bt,
                                                    float* __restrict__ C,
                                                    const float* __restrict__ w_scale,
                                                    const float* __restrict__ in_scale) {
    __shared__ int8_t lds[131072];

    const int tid  = threadIdx.x;
    const int lane = tid & 63;
    const int wave = tid >> 6;
    const int wr = wave >> 2;          // 0..1  (M half)
    const int wc = wave & 3;           // 0..3  (N quarter)
    const int lm = lane & 15;
    const int q  = lane >> 4;          // 16-B chunk within 64-B K-half

    // XCD-aware swizzle: 512 wgs, 8 XCDs, each XCD gets an 8x8 tile chunk.
    const int bid = blockIdx.x;
    const int xcd = bid & 7;
    const int j   = bid >> 3;
    const int bm  = (xcd >> 1) * 8 + (j >> 3);   // 0..31
    const int bn  = (xcd & 1) * 8 + (j & 7);     // 0..15

    // Staging: row = tid>>2; LDS slot (tid&3) gets global chunk (tid&3)^((row>>1)&3).
    const int srow  = tid >> 2;
    const int sperm = ((tid & 3) ^ ((tid >> 3) & 3)) << 4;
    const int8_t* gA = A  + (size_t)(bm * 256 + srow) * KDIM + sperm;
    const int8_t* gB = Bt + (size_t)(bn * 256 + srow) * KDIM + sperm;
    const int ldsT = tid * 16;

#define STAGE(MATBASE, GSRC, slot, ks, kbyte)                                              \
    lds_load16(GSRC + (kbyte) + (ks) * 64,                                                 \
               lds + (MATBASE) + (slot) * 32768 + (ks) * 16384 + ldsT);                    \
    lds_load16(GSRC + (kbyte) + (ks) * 64 + 524288,                                        \
               lds + (MATBASE) + (slot) * 32768 + (ks) * 16384 + 8192 + ldsT);

    // Fragment bases. row = wr*128 + mh*64 + mt*16 + lm; (row>>1)&3 == (lm>>1)&3.
    const int fsw = ((q ^ ((lm >> 1) & 3)) << 4);
    const int aB = (wr * 128 + lm) * 64 + fsw;
    const int bB = 65536 + (wc * 64 + lm) * 64 + fsw;

    v4i acc[8][4] = {{}};
    v4i av[2][4], bv[2][4];

#define RD(off) (*(const v4i*)(lds + (off)))
#define RGN(slot, ks) ((slot) * 32768 + (ks) * 16384)

#define IA(nb, slot, ks, mh)                                                               \
    av[nb][0] = RD(aB + RGN(slot, ks) + (mh) * 4096 + 0);                                  \
    av[nb][1] = RD(aB + RGN(slot, ks) + (mh) * 4096 + 1024);                               \
    av[nb][2] = RD(aB + RGN(slot, ks) + (mh) * 4096 + 2048);                               \
    av[nb][3] = RD(aB + RGN(slot, ks) + (mh) * 4096 + 3072);

#define IB(nb, slot, ks)                                                                   \
    bv[nb][0] = RD(bB + RGN(slot, ks) + 0);                                                \
    bv[nb][1] = RD(bB + RGN(slot, ks) + 1024);                                             \
    bv[nb][2] = RD(bB + RGN(slot, ks) + 2048);                                             \
    bv[nb][3] = RD(bB + RGN(slot, ks) + 3072);

#define VM6 asm volatile("s_waitcnt vmcnt(6)" ::: "memory");
#define VM4 asm volatile("s_waitcnt vmcnt(4)" ::: "memory");
#define VM2 asm volatile("s_waitcnt vmcnt(2)" ::: "memory");
#define VM0 asm volatile("s_waitcnt vmcnt(0)" ::: "memory");

// ISS: next phase's fragment reads. STG: stage or empty. GATEN = #reads in ISS.
#define PHASE(mh, AVC, BVC, ISS, STG, GATEN, VMW)                                          \
    {                                                                                      \
        ISS                                                                                \
        STG                                                                                \
        asm volatile("s_waitcnt lgkmcnt(" #GATEN ")" ::: "memory");                        \
        __builtin_amdgcn_sched_barrier(0);                                                 \
        __builtin_amdgcn_s_setprio(1);                                                     \
        _Pragma("unroll")                                                                  \
        for (int mt = 0; mt < 4; ++mt)                                                     \
            _Pragma("unroll")                                                              \
            for (int nt = 0; nt < 4; ++nt)                                                 \
                acc[(mh) * 4 + mt][nt] = __builtin_amdgcn_mfma_i32_16x16x64_i8(            \
                    av[AVC][mt], bv[BVC][nt], acc[(mh) * 4 + mt][nt], 0, 0, 0);            \
        __builtin_amdgcn_s_setprio(0);                                                     \
        __builtin_amdgcn_sched_barrier(0);                                                 \
        VMW                                                                                \
        __builtin_amdgcn_s_barrier();                                                      \
        __builtin_amdgcn_sched_barrier(0);                                                 \
    }

    // Prologue: tile0 both K-halves + tile1.k0 (12 loads/wave).
    STAGE(0, gA, 0, 0, 0) STAGE(65536, gB, 0, 0, 0)
    STAGE(0, gA, 0, 1, 0) STAGE(65536, gB, 0, 1, 0)
    STAGE(0, gA, 1, 0, 128) STAGE(65536, gB, 1, 0, 128)
    asm volatile("s_waitcnt vmcnt(8)" ::: "memory");   // tile0.k0 (s0.k0) landed
    __builtin_amdgcn_s_barrier();
    __builtin_amdgcn_sched_barrier(0);
    IB(0, 0, 0) IA(0, 0, 0, 0)                         // P0 fragments in flight

#pragma unroll 1
    for (int it = 0; it < 15; ++it) {
        const int kb = it * 256;
        PHASE(0, 0, 0, IA(1, 0, 0, 1),               STAGE(0, gA, 1, 1, kb + 128),     4, VM6)
        PHASE(1, 1, 0, IB(1, 0, 1) IA(0, 0, 1, 0),   STAGE(65536, gB, 1, 1, kb + 128), 8, VM6)
        PHASE(0, 0, 1, IA(1, 0, 1, 1),               STAGE(0, gA, 0, 0, kb + 256),     4, VM6)
        PHASE(1, 1, 1, IB(0, 1, 0) IA(0, 1, 0, 0),   STAGE(65536, gB, 0, 0, kb + 256), 8, VM6)
        PHASE(0, 0, 0, IA(1, 1, 0, 1),               STAGE(0, gA, 0, 1, kb + 256),     4, VM6)
        PHASE(1, 1, 0, IB(1, 1, 1) IA(0, 1, 1, 0),   STAGE(65536, gB, 0, 1, kb + 256), 8, VM6)
        PHASE(0, 0, 1, IA(1, 1, 1, 1),               STAGE(0, gA, 1, 0, kb + 384),     4, VM6)
        PHASE(1, 1, 1, IB(0, 0, 0) IA(0, 0, 0, 0),   STAGE(65536, gB, 1, 0, kb + 384), 8, VM6)
    }
    // Peeled last iteration (tiles 30, 31): only tile31.k1 still to stage.
    PHASE(0, 0, 0, IA(1, 0, 0, 1),               STAGE(0, gA, 1, 1, 3968),     4, VM6)
    PHASE(1, 1, 0, IB(1, 0, 1) IA(0, 0, 1, 0),   STAGE(65536, gB, 1, 1, 3968), 8, VM6)
    PHASE(0, 0, 1, IA(1, 0, 1, 1),               ,                             4, VM4)
    PHASE(1, 1, 1, IB(0, 1, 0) IA(0, 1, 0, 0),   ,                             8, VM2)
    PHASE(0, 0, 0, IA(1, 1, 0, 1),               ,                             4, VM0)
    PHASE(1, 1, 0, IB(1, 1, 1) IA(0, 1, 1, 0),   ,                             8, )
    PHASE(0, 0, 1, IA(1, 1, 1, 1),               ,                             4, )
    PHASE(1, 1, 1, ,                             ,                             0, )

    // Epilogue: D layout col = lane&15 (n), row = (lane>>4)*4 + reg (m).
    const float fs = w_scale[0] * in_scale[0];
    const int crow = q * 4;
#pragma unroll
    for (int m = 0; m < 8; ++m) {
#pragma unroll
        for (int n = 0; n < 4; ++n) {
            const size_t nn = (size_t)bn * 256 + wc * 64 + n * 16 + lm;
            const size_t mb = (size_t)bm * 256 + wr * 128 + m * 16 + crow;
#pragma unroll
            for (int r = 0; r < 4; ++r)
                C[(mb + r) * NDIM + nn] = (float)acc[m][n][r] * fs;
        }
    }

#undef STAGE
#undef RD
#undef RGN
#undef IA
#undef IB
#undef PHASE
#undef VM6
#undef VM4
#undef VM2
#undef VM0
}

extern "C" void kernel_launch(void* const* d_in, const int* in_sizes, int n_in,
                              void* d_out, int out_size, void* d_ws, size_t ws_size,
                              hipStream_t stream) {
    const float* x        = (const float*)d_in[0];
    const int*   w        = (const int*)d_in[1];
    const float* w_scale  = (const float*)d_in[2];
    const float* in_scale = (const float*)d_in[3];
    float* out = (float*)d_out;

    int8_t* xq = (int8_t*)d_ws;                       // 33,554,432 B
    int8_t* wq = xq + (size_t)MDIM * KDIM;            // 16,777,216 B (48 MB total)

    prep_k<<<QBLOCKS + WBLOCKS, 256, 0, stream>>>(
        (const float4*)x, (int4*)xq, (const int4*)w, (int4*)wq, in_scale);

    dim3 grid(512);
    gemm_i8_k<<<grid, 512, 0, stream>>>(xq, wq, out, w_scale, in_scale);
}